// Round 1
// baseline (305.560 us; speedup 1.0000x reference)
//
#include <hip/hip_runtime.h>

#define NH 32
#define HD 128
#define PBS 16
#define HIDDEN (NH * HD)   // 4096
#define QKVN (3 * HIDDEN)  // 12288

// out[b][n] = dot(x[b,:K], W[n,:K]) + bias[n]; one wave per row n, B=8 fixed.
__global__ __launch_bounds__(256) void gemv8(const float* __restrict__ x,
                                             const float* __restrict__ W,
                                             const float* __restrict__ bias,
                                             float* __restrict__ out,
                                             int N, int K) {
    const int lane = threadIdx.x & 63;
    const int gw   = (blockIdx.x * blockDim.x + threadIdx.x) >> 6;
    const int nwv  = (gridDim.x * blockDim.x) >> 6;
    for (int n = gw; n < N; n += nwv) {
        const float* wrow = W + (size_t)n * K;
        float acc[8];
#pragma unroll
        for (int b = 0; b < 8; ++b) acc[b] = 0.f;
        for (int k0 = lane * 4; k0 < K; k0 += 256) {
            const float4 w4 = *reinterpret_cast<const float4*>(wrow + k0);
#pragma unroll
            for (int b = 0; b < 8; ++b) {
                const float4 x4 = *reinterpret_cast<const float4*>(x + (size_t)b * K + k0);
                acc[b] += w4.x * x4.x + w4.y * x4.y + w4.z * x4.z + w4.w * x4.w;
            }
        }
#pragma unroll
        for (int b = 0; b < 8; ++b) {
#pragma unroll
            for (int off = 32; off > 0; off >>= 1)
                acc[b] += __shfl_xor(acc[b], off, 64);
        }
        if (lane == 0) {
            const float bv = bias ? bias[n] : 0.f;
#pragma unroll
            for (int b = 0; b < 8; ++b)
                out[(size_t)b * N + n] = acc[b] + bv;
        }
    }
}

// In-place RoPE on q and k halves of qkv ws. One thread per (part,b,h,d<64).
__global__ __launch_bounds__(256) void rope_k(float* __restrict__ qkv,
                                              const float* __restrict__ cosb,
                                              const float* __restrict__ sinb,
                                              int B) {
    const int tid = blockIdx.x * blockDim.x + threadIdx.x;
    const int total = 2 * B * NH * (HD / 2);
    if (tid >= total) return;
    const int d = tid % (HD / 2);
    const int h = (tid / (HD / 2)) % NH;
    const int b = (tid / (HD / 2) / NH) % B;
    const int part = tid / (HD / 2) / NH / B;  // 0=q, 1=k
    const float c = cosb[b * (HD / 2) + d];
    const float s = sinb[b * (HD / 2) + d];
    float* p = qkv + (size_t)b * QKVN + part * HIDDEN + h * HD + d;
    const float x1 = p[0];
    const float x2 = p[HD / 2];
    p[0]      = x1 * c - x2 * s;
    p[HD / 2] = x1 * s + x2 * c;
}

// One block per (b,h). 16 waves. Two passes: scores->LDS softmax->PV.
__global__ __launch_bounds__(1024) void attn_k(const float* __restrict__ qkv,
                                               const float* __restrict__ k_cache,
                                               const float* __restrict__ v_cache,
                                               const int* __restrict__ block_tables,
                                               const int* __restrict__ slots,
                                               const int* __restrict__ lengths,
                                               float* __restrict__ attn_out,
                                               int S, int max_blocks) {
    const int b = blockIdx.x >> 5;  // / NH
    const int h = blockIdx.x & 31;  // % NH
    extern __shared__ float smem[];
    float* sc  = smem;                   // S floats (scores, then reused as reduce buf)
    int*   bt  = (int*)(smem + S);       // max_blocks ints
    float* red = smem + S + max_blocks;  // 16 floats

    const int tid  = threadIdx.x;
    const int lane = tid & 63;
    const int wid  = tid >> 6;
    const int nw   = blockDim.x >> 6;

    for (int i = tid; i < max_blocks; i += blockDim.x)
        bt[i] = block_tables[b * max_blocks + i];
    __syncthreads();

    const int slot_b = slots[b];
    const int len    = lengths[b];
    const float scale = 0.088388347648318447f;  // 1/sqrt(128)

    const float* qp   = qkv + (size_t)b * QKVN + h * HD;
    const float* newk = qkv + (size_t)b * QKVN + HIDDEN + h * HD;
    const float* newv = qkv + (size_t)b * QKVN + 2 * HIDDEN + h * HD;
    const float2 q2 = *reinterpret_cast<const float2*>(qp + lane * 2);

    // Pass A: scores. Wave handles positions s = wid, wid+nw, ...
    for (int s = wid; s < S; s += nw) {
        const int idx = bt[s >> 4] * PBS + (s & (PBS - 1));
        const float* kp = (idx == slot_b) ? newk
                                          : (k_cache + (size_t)idx * HIDDEN + h * HD);
        const float2 k2 = *reinterpret_cast<const float2*>(kp + lane * 2);
        float p = q2.x * k2.x + q2.y * k2.y;
#pragma unroll
        for (int off = 32; off > 0; off >>= 1) p += __shfl_xor(p, off, 64);
        if (lane == 0) sc[s] = (s < len) ? p * scale : -1e30f;
    }
    __syncthreads();

    // Softmax over S in LDS.
    float m = -1e30f;
    for (int s = tid; s < S; s += blockDim.x) m = fmaxf(m, sc[s]);
#pragma unroll
    for (int off = 32; off > 0; off >>= 1) m = fmaxf(m, __shfl_xor(m, off, 64));
    if (lane == 0) red[wid] = m;
    __syncthreads();
    float bm = red[0];
    for (int w = 1; w < nw; ++w) bm = fmaxf(bm, red[w]);
    __syncthreads();

    float lsum = 0.f;
    for (int s = tid; s < S; s += blockDim.x) {
        const float e = __expf(sc[s] - bm);
        sc[s] = e;
        lsum += e;
    }
#pragma unroll
    for (int off = 32; off > 0; off >>= 1) lsum += __shfl_xor(lsum, off, 64);
    if (lane == 0) red[wid] = lsum;
    __syncthreads();
    float tot = 0.f;
    for (int w = 0; w < nw; ++w) tot += red[w];
    const float inv = 1.f / tot;

    // Pass B: attn[d] = sum_s p[s] * v[s][d]; lane owns d = lane*2, lane*2+1.
    float a0 = 0.f, a1 = 0.f;
    for (int s = wid; s < S; s += nw) {
        const int idx = bt[s >> 4] * PBS + (s & (PBS - 1));
        const float* vp = (idx == slot_b) ? newv
                                          : (v_cache + (size_t)idx * HIDDEN + h * HD);
        const float2 v2 = *reinterpret_cast<const float2*>(vp + lane * 2);
        const float p = sc[s];
        a0 += p * v2.x;
        a1 += p * v2.y;
    }
    __syncthreads();  // done reading sc; reuse as cross-wave reduce buffer
    sc[wid * HD + lane * 2]     = a0;
    sc[wid * HD + lane * 2 + 1] = a1;
    __syncthreads();
    if (wid == 0) {
        float t0 = 0.f, t1 = 0.f;
        for (int w = 0; w < nw; ++w) {
            t0 += sc[w * HD + lane * 2];
            t1 += sc[w * HD + lane * 2 + 1];
        }
        attn_out[(size_t)b * HIDDEN + h * HD + lane * 2]     = t0 * inv;
        attn_out[(size_t)b * HIDDEN + h * HD + lane * 2 + 1] = t1 * inv;
    }
}

extern "C" void kernel_launch(void* const* d_in, const int* in_sizes, int n_in,
                              void* d_out, int out_size, void* d_ws, size_t ws_size,
                              hipStream_t stream) {
    const float* hidden  = (const float*)d_in[0];
    const float* cosb    = (const float*)d_in[1];
    const float* sinb    = (const float*)d_in[2];
    const float* w_qkv   = (const float*)d_in[3];
    const float* b_qkv   = (const float*)d_in[4];
    const float* w_o     = (const float*)d_in[5];
    const float* k_cache = (const float*)d_in[6];
    const float* v_cache = (const float*)d_in[7];
    const int*   btab    = (const int*)d_in[8];
    const int*   slots   = (const int*)d_in[9];
    const int*   lens    = (const int*)d_in[10];
    // d_in[11] = max_s (device scalar) — S derived from block_tables size instead.

    const int B = in_sizes[0] / HIDDEN;      // 8
    const int max_blocks = in_sizes[8] / B;  // 128
    const int S = max_blocks * PBS;          // 2048

    float* qkv  = (float*)d_ws;                  // [B][QKVN]
    float* attn = qkv + (size_t)B * QKVN;        // [B][HIDDEN]
    float* out  = (float*)d_out;

    // 1) qkv = hidden @ w_qkv^T + b_qkv   (one wave per output row)
    gemv8<<<QKVN / 4, 256, 0, stream>>>(hidden, w_qkv, b_qkv, qkv, QKVN, HIDDEN);

    // 2) RoPE on q and k
    {
        const int total = 2 * B * NH * (HD / 2);
        rope_k<<<(total + 255) / 256, 256, 0, stream>>>(qkv, cosb, sinb, B);
    }

    // 3) paged attention (fresh k/v substituted at idx == slots[b])
    {
        const size_t smem = (size_t)(S + max_blocks + 16) * sizeof(float);
        attn_k<<<B * NH, 1024, smem, stream>>>(qkv, k_cache, v_cache, btab, slots,
                                               lens, attn, S, max_blocks);
    }

    // 4) out = attn @ w_o^T
    gemv8<<<HIDDEN / 4, 256, 0, stream>>>(attn, w_o, nullptr, out, HIDDEN, HIDDEN);
}

// Round 2
// 228.383 us; speedup vs baseline: 1.3379x; 1.3379x over previous
//
#include <hip/hip_runtime.h>

#define NH 32
#define HD 128
#define PBS 16
#define HIDDEN (NH * HD)   // 4096
#define QKVN (3 * HIDDEN)  // 12288

// out[b][n] = dot(x[b,:K], W[n,:K]) + bias[n]; one wave per row n, B=8 fixed.
__global__ __launch_bounds__(256) void gemv8(const float* __restrict__ x,
                                             const float* __restrict__ W,
                                             const float* __restrict__ bias,
                                             float* __restrict__ out,
                                             int N, int K) {
    const int lane = threadIdx.x & 63;
    const int gw   = (blockIdx.x * blockDim.x + threadIdx.x) >> 6;
    const int nwv  = (gridDim.x * blockDim.x) >> 6;
    for (int n = gw; n < N; n += nwv) {
        const float* wrow = W + (size_t)n * K;
        float acc[8];
#pragma unroll
        for (int b = 0; b < 8; ++b) acc[b] = 0.f;
        for (int k0 = lane * 4; k0 < K; k0 += 256) {
            const float4 w4 = *reinterpret_cast<const float4*>(wrow + k0);
#pragma unroll
            for (int b = 0; b < 8; ++b) {
                const float4 x4 = *reinterpret_cast<const float4*>(x + (size_t)b * K + k0);
                acc[b] += w4.x * x4.x + w4.y * x4.y + w4.z * x4.z + w4.w * x4.w;
            }
        }
#pragma unroll
        for (int b = 0; b < 8; ++b) {
#pragma unroll
            for (int off = 32; off > 0; off >>= 1)
                acc[b] += __shfl_xor(acc[b], off, 64);
        }
        if (lane == 0) {
            const float bv = bias ? bias[n] : 0.f;
#pragma unroll
            for (int b = 0; b < 8; ++b)
                out[(size_t)b * N + n] = acc[b] + bv;
        }
    }
}

// In-place RoPE on q and k halves of qkv ws. One thread per (part,b,h,d<64).
__global__ __launch_bounds__(256) void rope_k(float* __restrict__ qkv,
                                              const float* __restrict__ cosb,
                                              const float* __restrict__ sinb,
                                              int B) {
    const int tid = blockIdx.x * blockDim.x + threadIdx.x;
    const int total = 2 * B * NH * (HD / 2);
    if (tid >= total) return;
    const int d = tid % (HD / 2);
    const int h = (tid / (HD / 2)) % NH;
    const int b = (tid / (HD / 2) / NH) % B;
    const int part = tid / (HD / 2) / NH / B;  // 0=q, 1=k
    const float c = cosb[b * (HD / 2) + d];
    const float s = sinb[b * (HD / 2) + d];
    float* p = qkv + (size_t)b * QKVN + part * HIDDEN + h * HD + d;
    const float x1 = p[0];
    const float x2 = p[HD / 2];
    p[0]      = x1 * c - x2 * s;
    p[HD / 2] = x1 * s + x2 * c;
}

// One block per (b,h). 16 waves. Half-wave (32 lanes) per position, float4
// loads, U=8 unroll => 8 independent 1KB load instrs in flight per wave.
__global__ __launch_bounds__(1024) void attn_k(const float* __restrict__ qkv,
                                               const float* __restrict__ k_cache,
                                               const float* __restrict__ v_cache,
                                               const int* __restrict__ block_tables,
                                               const int* __restrict__ slots,
                                               const int* __restrict__ lengths,
                                               float* __restrict__ attn_out,
                                               int S, int max_blocks) {
    const int b = blockIdx.x >> 5;  // / NH
    const int h = blockIdx.x & 31;  // % NH
    extern __shared__ float smem[];
    float* sc  = smem;                   // S floats (scores/probs, reused as reduce buf)
    int*   bt  = (int*)(smem + S);       // max_blocks ints
    float* red = smem + S + max_blocks;  // 16 floats

    const int tid  = threadIdx.x;
    const int lane = tid & 63;
    const int wid  = tid >> 6;
    const int nw   = blockDim.x >> 6;   // 16
    const int half = lane >> 5;          // 0 or 1
    const int l32  = lane & 31;

    for (int i = tid; i < max_blocks; i += blockDim.x)
        bt[i] = block_tables[b * max_blocks + i];
    __syncthreads();

    const int slot_b = slots[b];
    const int len    = lengths[b];
    const float scale = 0.088388347648318447f;  // 1/sqrt(128)

    const float* qp   = qkv + (size_t)b * QKVN + h * HD;
    const float* newk = qkv + (size_t)b * QKVN + HIDDEN + h * HD;
    const float* newv = qkv + (size_t)b * QKVN + 2 * HIDDEN + h * HD;
    const float4 q4 = *reinterpret_cast<const float4*>(qp + l32 * 4);

    // ---- Pass A: scores. Wave handles 16 positions per iteration (U=8 x 2 halves).
    const int STEP = nw * 16;  // 256
    for (int s0 = wid * 16; s0 < S; s0 += STEP) {
        float4 k4[8];
        int pos[8];
#pragma unroll
        for (int u = 0; u < 8; ++u) {
            const int p = s0 + u * 2 + half;
            pos[u] = p;
            const int idx = bt[p >> 4] * PBS + (p & (PBS - 1));
            const float* kp = (idx == slot_b) ? newk
                                              : (k_cache + (size_t)idx * HIDDEN + h * HD);
            k4[u] = *reinterpret_cast<const float4*>(kp + l32 * 4);
        }
#pragma unroll
        for (int u = 0; u < 8; ++u) {
            float d = k4[u].x * q4.x + k4[u].y * q4.y + k4[u].z * q4.z + k4[u].w * q4.w;
#pragma unroll
            for (int off = 16; off > 0; off >>= 1) d += __shfl_xor(d, off, 64);
            if (l32 == 0) sc[pos[u]] = (pos[u] < len) ? d * scale : -1e30f;
        }
    }
    __syncthreads();

    // ---- Softmax over S in LDS.
    float m = -1e30f;
    for (int s = tid; s < S; s += blockDim.x) m = fmaxf(m, sc[s]);
#pragma unroll
    for (int off = 32; off > 0; off >>= 1) m = fmaxf(m, __shfl_xor(m, off, 64));
    if (lane == 0) red[wid] = m;
    __syncthreads();
    float bm = red[0];
    for (int w = 1; w < nw; ++w) bm = fmaxf(bm, red[w]);
    __syncthreads();

    float lsum = 0.f;
    for (int s = tid; s < S; s += blockDim.x) {
        const float e = __expf(sc[s] - bm);
        sc[s] = e;
        lsum += e;
    }
#pragma unroll
    for (int off = 32; off > 0; off >>= 1) lsum += __shfl_xor(lsum, off, 64);
    if (lane == 0) red[wid] = lsum;
    __syncthreads();
    float tot = 0.f;
    for (int w = 0; w < nw; ++w) tot += red[w];
    const float inv = 1.f / tot;

    // ---- Pass B: attn[d] = sum_s p[s]*v[s][d]. Half-wave per position, float4/lane.
    float4 acc[8];
#pragma unroll
    for (int u = 0; u < 8; ++u) acc[u] = make_float4(0.f, 0.f, 0.f, 0.f);
    for (int s0 = wid * 16; s0 < S; s0 += STEP) {
        float4 v4[8];
        float pr[8];
#pragma unroll
        for (int u = 0; u < 8; ++u) {
            const int p = s0 + u * 2 + half;
            const int idx = bt[p >> 4] * PBS + (p & (PBS - 1));
            const float* vp = (idx == slot_b) ? newv
                                              : (v_cache + (size_t)idx * HIDDEN + h * HD);
            v4[u] = *reinterpret_cast<const float4*>(vp + l32 * 4);
            pr[u] = sc[p];
        }
#pragma unroll
        for (int u = 0; u < 8; ++u) {
            acc[u].x += pr[u] * v4[u].x;
            acc[u].y += pr[u] * v4[u].y;
            acc[u].z += pr[u] * v4[u].z;
            acc[u].w += pr[u] * v4[u].w;
        }
    }
    float4 a = acc[0];
#pragma unroll
    for (int u = 1; u < 8; ++u) {
        a.x += acc[u].x; a.y += acc[u].y; a.z += acc[u].z; a.w += acc[u].w;
    }
    // combine the two halves (even/odd positions)
    a.x += __shfl_xor(a.x, 32, 64);
    a.y += __shfl_xor(a.y, 32, 64);
    a.z += __shfl_xor(a.z, 32, 64);
    a.w += __shfl_xor(a.w, 32, 64);

    __syncthreads();  // all waves done reading sc; reuse as cross-wave reduce buffer
    if (half == 0)
        *reinterpret_cast<float4*>(&sc[wid * HD + l32 * 4]) = a;
    __syncthreads();
    if (wid == 0) {
        float t0 = 0.f, t1 = 0.f;
        for (int w = 0; w < nw; ++w) {
            t0 += sc[w * HD + lane * 2];
            t1 += sc[w * HD + lane * 2 + 1];
        }
        attn_out[(size_t)b * HIDDEN + h * HD + lane * 2]     = t0 * inv;
        attn_out[(size_t)b * HIDDEN + h * HD + lane * 2 + 1] = t1 * inv;
    }
}

extern "C" void kernel_launch(void* const* d_in, const int* in_sizes, int n_in,
                              void* d_out, int out_size, void* d_ws, size_t ws_size,
                              hipStream_t stream) {
    const float* hidden  = (const float*)d_in[0];
    const float* cosb    = (const float*)d_in[1];
    const float* sinb    = (const float*)d_in[2];
    const float* w_qkv   = (const float*)d_in[3];
    const float* b_qkv   = (const float*)d_in[4];
    const float* w_o     = (const float*)d_in[5];
    const float* k_cache = (const float*)d_in[6];
    const float* v_cache = (const float*)d_in[7];
    const int*   btab    = (const int*)d_in[8];
    const int*   slots   = (const int*)d_in[9];
    const int*   lens    = (const int*)d_in[10];

    const int B = in_sizes[0] / HIDDEN;      // 8
    const int max_blocks = in_sizes[8] / B;  // 128
    const int S = max_blocks * PBS;          // 2048

    float* qkv  = (float*)d_ws;                  // [B][QKVN]
    float* attn = qkv + (size_t)B * QKVN;        // [B][HIDDEN]
    float* out  = (float*)d_out;

    // 1) qkv = hidden @ w_qkv^T + b_qkv
    gemv8<<<QKVN / 4, 256, 0, stream>>>(hidden, w_qkv, b_qkv, qkv, QKVN, HIDDEN);

    // 2) RoPE on q and k
    {
        const int total = 2 * B * NH * (HD / 2);
        rope_k<<<(total + 255) / 256, 256, 0, stream>>>(qkv, cosb, sinb, B);
    }

    // 3) paged attention (fresh k/v substituted at idx == slots[b])
    {
        const size_t smem = (size_t)(S + max_blocks + 16) * sizeof(float);
        attn_k<<<B * NH, 1024, smem, stream>>>(qkv, k_cache, v_cache, btab, slots,
                                               lens, attn, S, max_blocks);
    }

    // 4) out = attn @ w_o^T
    gemv8<<<HIDDEN / 4, 256, 0, stream>>>(attn, w_o, nullptr, out, HIDDEN, HIDDEN);
}

// Round 5
// 211.836 us; speedup vs baseline: 1.4424x; 1.0781x over previous
//
#include <hip/hip_runtime.h>

#define NH 32
#define HD 128
#define PBS 16
#define HIDDEN (NH * HD)   // 4096
#define QKVN (3 * HIDDEN)  // 12288
#define NSPLIT 4

// out[b][n] = dot(x[b,:K], W[n,:K]) + bias[n]; one wave per row n, B=8 fixed.
__global__ __launch_bounds__(256) void gemv8(const float* __restrict__ x,
                                             const float* __restrict__ W,
                                             const float* __restrict__ bias,
                                             float* __restrict__ out,
                                             int N, int K) {
    const int lane = threadIdx.x & 63;
    const int gw   = (blockIdx.x * blockDim.x + threadIdx.x) >> 6;
    const int nwv  = (gridDim.x * blockDim.x) >> 6;
    for (int n = gw; n < N; n += nwv) {
        const float* wrow = W + (size_t)n * K;
        float acc[8];
#pragma unroll
        for (int b = 0; b < 8; ++b) acc[b] = 0.f;
#pragma unroll 4
        for (int k0 = lane * 4; k0 < K; k0 += 256) {
            const float4 w4 = *reinterpret_cast<const float4*>(wrow + k0);
#pragma unroll
            for (int b = 0; b < 8; ++b) {
                const float4 x4 = *reinterpret_cast<const float4*>(x + (size_t)b * K + k0);
                acc[b] += w4.x * x4.x + w4.y * x4.y + w4.z * x4.z + w4.w * x4.w;
            }
        }
#pragma unroll
        for (int b = 0; b < 8; ++b) {
#pragma unroll
            for (int off = 32; off > 0; off >>= 1)
                acc[b] += __shfl_xor(acc[b], off, 64);
        }
        if (lane == 0) {
            const float bv = bias ? bias[n] : 0.f;
#pragma unroll
            for (int b = 0; b < 8; ++b)
                out[(size_t)b * N + n] = acc[b] + bv;
        }
    }
}

// In-place RoPE on q and k halves of qkv ws. One thread per (part,b,h,d<64).
__global__ __launch_bounds__(256) void rope_k(float* __restrict__ qkv,
                                              const float* __restrict__ cosb,
                                              const float* __restrict__ sinb,
                                              int B) {
    const int tid = blockIdx.x * blockDim.x + threadIdx.x;
    const int total = 2 * B * NH * (HD / 2);
    if (tid >= total) return;
    const int d = tid % (HD / 2);
    const int h = (tid / (HD / 2)) % NH;
    const int b = (tid / (HD / 2) / NH) % B;
    const int part = tid / (HD / 2) / NH / B;  // 0=q, 1=k
    const float c = cosb[b * (HD / 2) + d];
    const float s = sinb[b * (HD / 2) + d];
    float* p = qkv + (size_t)b * QKVN + part * HIDDEN + h * HD + d;
    const float x1 = p[0];
    const float x2 = p[HD / 2];
    p[0]      = x1 * c - x2 * s;
    p[HD / 2] = x1 * s + x2 * c;
}

// Flash-style partial: one block per (b,h,split). 512 threads = 8 waves.
// Half-wave (32 lanes) per position, float4 loads, U=8 unroll.
// Writes unnormalized o (HD floats) + (m,l) per partial.
__global__ __launch_bounds__(512) void attn_part(const float* __restrict__ qkv,
                                                 const float* __restrict__ k_cache,
                                                 const float* __restrict__ v_cache,
                                                 const int* __restrict__ block_tables,
                                                 const int* __restrict__ slots,
                                                 const int* __restrict__ lengths,
                                                 float* __restrict__ part_o,
                                                 float* __restrict__ part_ml,
                                                 int S, int max_blocks) {
    const int split = blockIdx.x & (NSPLIT - 1);
    const int bh    = blockIdx.x >> 2;  // log2(NSPLIT)
    const int b     = bh >> 5;
    const int h     = bh & 31;
    const int SP    = S / NSPLIT;       // 512
    const int base  = split * SP;

    extern __shared__ float smem[];
    float* sc    = smem;                       // SP floats
    int*   bt    = (int*)(smem + SP);          // SP/PBS ints
    float* red   = smem + SP + SP / PBS;       // 16 floats
    float* stage = red + 16;                   // 8*HD floats

    const int tid  = threadIdx.x;
    const int lane = tid & 63;
    const int wid  = tid >> 6;
    const int nw   = blockDim.x >> 6;   // 8
    const int half = lane >> 5;
    const int l32  = lane & 31;

    const int nbt = SP / PBS;  // 32
    for (int i = tid; i < nbt; i += blockDim.x)
        bt[i] = block_tables[b * max_blocks + base / PBS + i];
    __syncthreads();

    const int slot_b = slots[b];
    const int len    = lengths[b];
    const float scale = 0.088388347648318447f;  // 1/sqrt(128)

    const float* qp   = qkv + (size_t)b * QKVN + h * HD;
    const float* newk = qkv + (size_t)b * QKVN + HIDDEN + h * HD;
    const float* newv = qkv + (size_t)b * QKVN + 2 * HIDDEN + h * HD;
    const float4 q4 = *reinterpret_cast<const float4*>(qp + l32 * 4);

    // ---- Pass A: scores for local positions [0, SP).
    const int STEP = nw * 16;  // 128
    for (int s0 = wid * 16; s0 < SP; s0 += STEP) {
        float4 k4[8];
#pragma unroll
        for (int u = 0; u < 8; ++u) {
            const int p = s0 + u * 2 + half;
            const int idx = bt[p >> 4] * PBS + (p & (PBS - 1));
            const float* kp = (idx == slot_b) ? newk
                                              : (k_cache + (size_t)idx * HIDDEN + h * HD);
            k4[u] = *reinterpret_cast<const float4*>(kp + l32 * 4);
        }
#pragma unroll
        for (int u = 0; u < 8; ++u) {
            const int p = s0 + u * 2 + half;
            float d = k4[u].x * q4.x + k4[u].y * q4.y + k4[u].z * q4.z + k4[u].w * q4.w;
#pragma unroll
            for (int off = 16; off > 0; off >>= 1) d += __shfl_xor(d, off, 64);
            if (l32 == 0) sc[p] = (base + p < len) ? d * scale : -1e30f;
        }
    }
    __syncthreads();

    // ---- Local softmax over SP in LDS.
    float m = -1e30f;
    for (int s = tid; s < SP; s += blockDim.x) m = fmaxf(m, sc[s]);
#pragma unroll
    for (int off = 32; off > 0; off >>= 1) m = fmaxf(m, __shfl_xor(m, off, 64));
    if (lane == 0) red[wid] = m;
    __syncthreads();
    float bm = red[0];
    for (int w = 1; w < nw; ++w) bm = fmaxf(bm, red[w]);
    __syncthreads();

    float lsum = 0.f;
    for (int s = tid; s < SP; s += blockDim.x) {
        const float e = __expf(sc[s] - bm);
        sc[s] = e;
        lsum += e;
    }
#pragma unroll
    for (int off = 32; off > 0; off >>= 1) lsum += __shfl_xor(lsum, off, 64);
    if (lane == 0) red[wid] = lsum;
    __syncthreads();
    float tot = 0.f;
    for (int w = 0; w < nw; ++w) tot += red[w];

    // ---- Pass B: o[d] = sum_s e[s]*v[s][d] (unnormalized).
    float4 acc[8];
#pragma unroll
    for (int u = 0; u < 8; ++u) acc[u] = make_float4(0.f, 0.f, 0.f, 0.f);
    for (int s0 = wid * 16; s0 < SP; s0 += STEP) {
        float4 v4[8];
        float pr[8];
#pragma unroll
        for (int u = 0; u < 8; ++u) {
            const int p = s0 + u * 2 + half;
            const int idx = bt[p >> 4] * PBS + (p & (PBS - 1));
            const float* vp = (idx == slot_b) ? newv
                                              : (v_cache + (size_t)idx * HIDDEN + h * HD);
            v4[u] = *reinterpret_cast<const float4*>(vp + l32 * 4);
            pr[u] = sc[p];
        }
#pragma unroll
        for (int u = 0; u < 8; ++u) {
            acc[u].x += pr[u] * v4[u].x;
            acc[u].y += pr[u] * v4[u].y;
            acc[u].z += pr[u] * v4[u].z;
            acc[u].w += pr[u] * v4[u].w;
        }
    }
    float4 a = acc[0];
#pragma unroll
    for (int u = 1; u < 8; ++u) {
        a.x += acc[u].x; a.y += acc[u].y; a.z += acc[u].z; a.w += acc[u].w;
    }
    a.x += __shfl_xor(a.x, 32, 64);
    a.y += __shfl_xor(a.y, 32, 64);
    a.z += __shfl_xor(a.z, 32, 64);
    a.w += __shfl_xor(a.w, 32, 64);

    if (half == 0)
        *reinterpret_cast<float4*>(&stage[wid * HD + l32 * 4]) = a;
    __syncthreads();
    if (wid == 0) {
        float t0 = 0.f, t1 = 0.f;
        for (int w = 0; w < nw; ++w) {
            t0 += stage[w * HD + lane * 2];
            t1 += stage[w * HD + lane * 2 + 1];
        }
        float* po = part_o + ((size_t)bh * NSPLIT + split) * HD;
        po[lane * 2]     = t0;
        po[lane * 2 + 1] = t1;
        if (lane == 0) {
            part_ml[((size_t)bh * NSPLIT + split) * 2]     = bm;
            part_ml[((size_t)bh * NSPLIT + split) * 2 + 1] = tot;
        }
    }
}

// Combine NSPLIT partials per (b,h). One block per bh, HD threads.
__global__ __launch_bounds__(HD) void attn_reduce(const float* __restrict__ part_o,
                                                  const float* __restrict__ part_ml,
                                                  float* __restrict__ attn_out) {
    const int bh = blockIdx.x;
    const int d  = threadIdx.x;
    float M = -1e30f;
#pragma unroll
    for (int i = 0; i < NSPLIT; ++i)
        M = fmaxf(M, part_ml[((size_t)bh * NSPLIT + i) * 2]);
    float L = 0.f, o = 0.f;
#pragma unroll
    for (int i = 0; i < NSPLIT; ++i) {
        const float mi = part_ml[((size_t)bh * NSPLIT + i) * 2];
        const float li = part_ml[((size_t)bh * NSPLIT + i) * 2 + 1];
        const float w  = __expf(mi - M);
        L += li * w;
        o += part_o[((size_t)bh * NSPLIT + i) * HD + d] * w;
    }
    attn_out[(size_t)bh * HD + d] = o / L;
}

extern "C" void kernel_launch(void* const* d_in, const int* in_sizes, int n_in,
                              void* d_out, int out_size, void* d_ws, size_t ws_size,
                              hipStream_t stream) {
    const float* hidden  = (const float*)d_in[0];
    const float* cosb    = (const float*)d_in[1];
    const float* sinb    = (const float*)d_in[2];
    const float* w_qkv   = (const float*)d_in[3];
    const float* b_qkv   = (const float*)d_in[4];
    const float* w_o     = (const float*)d_in[5];
    const float* k_cache = (const float*)d_in[6];
    const float* v_cache = (const float*)d_in[7];
    const int*   btab    = (const int*)d_in[8];
    const int*   slots   = (const int*)d_in[9];
    const int*   lens    = (const int*)d_in[10];

    const int B = in_sizes[0] / HIDDEN;      // 8
    const int max_blocks = in_sizes[8] / B;  // 128
    const int S = max_blocks * PBS;          // 2048

    float* qkv     = (float*)d_ws;                        // [B][QKVN]
    float* attn    = qkv + (size_t)B * QKVN;              // [B][HIDDEN]
    float* part_o  = attn + (size_t)B * HIDDEN;           // [B*NH*NSPLIT][HD]
    float* part_ml = part_o + (size_t)B * NH * NSPLIT * HD;  // [B*NH*NSPLIT][2]
    float* out     = (float*)d_out;

    // 1) qkv = hidden @ w_qkv^T + b_qkv
    gemv8<<<QKVN / 4, 256, 0, stream>>>(hidden, w_qkv, b_qkv, qkv, QKVN, HIDDEN);

    // 2) RoPE on q and k
    {
        const int total = 2 * B * NH * (HD / 2);
        rope_k<<<(total + 255) / 256, 256, 0, stream>>>(qkv, cosb, sinb, B);
    }

    // 3) paged attention partials + reduce
    {
        const int SP = S / NSPLIT;
        const size_t smem = (size_t)(SP + SP / PBS + 16 + 8 * HD) * sizeof(float);
        attn_part<<<B * NH * NSPLIT, 512, smem, stream>>>(qkv, k_cache, v_cache,
                                                          btab, slots, lens,
                                                          part_o, part_ml, S, max_blocks);
        attn_reduce<<<B * NH, HD, 0, stream>>>(part_o, part_ml, attn);
    }

    // 4) out = attn @ w_o^T
    gemv8<<<HIDDEN / 4, 256, 0, stream>>>(attn, w_o, nullptr, out, HIDDEN, HIDDEN);
}

// Round 6
// 205.731 us; speedup vs baseline: 1.4852x; 1.0297x over previous
//
#include <hip/hip_runtime.h>

#define NH 32
#define HD 128
#define PBS 16
#define HIDDEN (NH * HD)   // 4096
#define QKVN (3 * HIDDEN)  // 12288
#define NSPLIT 8

// out[b][n] = dot(x[b,:K], W[n,:K]) + bias[n], B=8 fixed.
// NR=4 rows per wave: x (L1) loads amortized over 4 weight rows.
__global__ __launch_bounds__(256) void gemv4r(const float* __restrict__ x,
                                              const float* __restrict__ W,
                                              const float* __restrict__ bias,
                                              float* __restrict__ out,
                                              int N, int K) {
    const int lane = threadIdx.x & 63;
    const int wv   = (blockIdx.x * blockDim.x + threadIdx.x) >> 6;
    const int n0   = wv * 4;
    if (n0 >= N) return;
    const float* w0 = W + (size_t)n0 * K;

    float acc[4][8];
#pragma unroll
    for (int r = 0; r < 4; ++r)
#pragma unroll
        for (int b = 0; b < 8; ++b) acc[r][b] = 0.f;

#pragma unroll 2
    for (int k0 = lane * 4; k0 < K; k0 += 256) {
        float4 w4[4];
#pragma unroll
        for (int r = 0; r < 4; ++r)
            w4[r] = *reinterpret_cast<const float4*>(w0 + (size_t)r * K + k0);
#pragma unroll
        for (int b = 0; b < 8; ++b) {
            const float4 x4 = *reinterpret_cast<const float4*>(x + (size_t)b * K + k0);
#pragma unroll
            for (int r = 0; r < 4; ++r)
                acc[r][b] += w4[r].x * x4.x + w4[r].y * x4.y +
                             w4[r].z * x4.z + w4[r].w * x4.w;
        }
    }
#pragma unroll
    for (int r = 0; r < 4; ++r)
#pragma unroll
        for (int b = 0; b < 8; ++b)
#pragma unroll
            for (int off = 32; off > 0; off >>= 1)
                acc[r][b] += __shfl_xor(acc[r][b], off, 64);
    if (lane == 0) {
#pragma unroll
        for (int r = 0; r < 4; ++r) {
            const float bv = bias ? bias[n0 + r] : 0.f;
#pragma unroll
            for (int b = 0; b < 8; ++b)
                out[(size_t)b * N + n0 + r] = acc[r][b] + bv;
        }
    }
}

// In-place RoPE on q and k halves of qkv ws. One thread per (part,b,h,d<64).
__global__ __launch_bounds__(256) void rope_k(float* __restrict__ qkv,
                                              const float* __restrict__ cosb,
                                              const float* __restrict__ sinb,
                                              int B) {
    const int tid = blockIdx.x * blockDim.x + threadIdx.x;
    const int total = 2 * B * NH * (HD / 2);
    if (tid >= total) return;
    const int d = tid % (HD / 2);
    const int h = (tid / (HD / 2)) % NH;
    const int b = (tid / (HD / 2) / NH) % B;
    const int part = tid / (HD / 2) / NH / B;  // 0=q, 1=k
    const float c = cosb[b * (HD / 2) + d];
    const float s = sinb[b * (HD / 2) + d];
    float* p = qkv + (size_t)b * QKVN + part * HIDDEN + h * HD + d;
    const float x1 = p[0];
    const float x2 = p[HD / 2];
    p[0]      = x1 * c - x2 * s;
    p[HD / 2] = x1 * s + x2 * c;
}

// Flash-style partial: one block per (b,h,split). 256 threads = 4 waves
// (8 blocks/CU resident). Half-wave per position, float4 loads, U=8 unroll.
__global__ __launch_bounds__(256) void attn_part(const float* __restrict__ qkv,
                                                 const float* __restrict__ k_cache,
                                                 const float* __restrict__ v_cache,
                                                 const int* __restrict__ block_tables,
                                                 const int* __restrict__ slots,
                                                 const int* __restrict__ lengths,
                                                 float* __restrict__ part_o,
                                                 float* __restrict__ part_ml,
                                                 int S, int max_blocks) {
    const int split = blockIdx.x % NSPLIT;
    const int bh    = blockIdx.x / NSPLIT;
    const int b     = bh >> 5;
    const int h     = bh & 31;
    const int SP    = S / NSPLIT;       // 256
    const int base  = split * SP;

    extern __shared__ float smem[];
    float* sc    = smem;                       // SP floats
    int*   bt    = (int*)(smem + SP);          // SP/PBS ints
    float* red   = smem + SP + SP / PBS;       // 16 floats
    float* stage = red + 16;                   // nw*HD floats

    const int tid  = threadIdx.x;
    const int lane = tid & 63;
    const int wid  = tid >> 6;
    const int nw   = blockDim.x >> 6;   // 4
    const int half = lane >> 5;
    const int l32  = lane & 31;

    const int nbt = SP / PBS;  // 16
    for (int i = tid; i < nbt; i += blockDim.x)
        bt[i] = block_tables[b * max_blocks + base / PBS + i];
    __syncthreads();

    const int slot_b = slots[b];
    const int len    = lengths[b];
    const float scale = 0.088388347648318447f;  // 1/sqrt(128)

    const float* qp   = qkv + (size_t)b * QKVN + h * HD;
    const float* newk = qkv + (size_t)b * QKVN + HIDDEN + h * HD;
    const float* newv = qkv + (size_t)b * QKVN + 2 * HIDDEN + h * HD;
    const float4 q4 = *reinterpret_cast<const float4*>(qp + l32 * 4);

    // ---- Pass A: scores for local positions [0, SP).
    const int STEP = nw * 16;  // 64
    for (int s0 = wid * 16; s0 < SP; s0 += STEP) {
        float4 k4[8];
#pragma unroll
        for (int u = 0; u < 8; ++u) {
            const int p = s0 + u * 2 + half;
            const int idx = bt[p >> 4] * PBS + (p & (PBS - 1));
            const float* kp = (idx == slot_b) ? newk
                                              : (k_cache + (size_t)idx * HIDDEN + h * HD);
            k4[u] = *reinterpret_cast<const float4*>(kp + l32 * 4);
        }
#pragma unroll
        for (int u = 0; u < 8; ++u) {
            const int p = s0 + u * 2 + half;
            float d = k4[u].x * q4.x + k4[u].y * q4.y + k4[u].z * q4.z + k4[u].w * q4.w;
#pragma unroll
            for (int off = 16; off > 0; off >>= 1) d += __shfl_xor(d, off, 64);
            if (l32 == 0) sc[p] = (base + p < len) ? d * scale : -1e30f;
        }
    }
    __syncthreads();

    // ---- Local softmax over SP in LDS.
    float m = -1e30f;
    for (int s = tid; s < SP; s += blockDim.x) m = fmaxf(m, sc[s]);
#pragma unroll
    for (int off = 32; off > 0; off >>= 1) m = fmaxf(m, __shfl_xor(m, off, 64));
    if (lane == 0) red[wid] = m;
    __syncthreads();
    float bm = red[0];
    for (int w = 1; w < nw; ++w) bm = fmaxf(bm, red[w]);
    __syncthreads();

    float lsum = 0.f;
    for (int s = tid; s < SP; s += blockDim.x) {
        const float e = __expf(sc[s] - bm);
        sc[s] = e;
        lsum += e;
    }
#pragma unroll
    for (int off = 32; off > 0; off >>= 1) lsum += __shfl_xor(lsum, off, 64);
    if (lane == 0) red[wid] = lsum;
    __syncthreads();
    float tot = 0.f;
    for (int w = 0; w < nw; ++w) tot += red[w];

    // ---- Pass B: o[d] = sum_s e[s]*v[s][d] (unnormalized).
    float4 acc[8];
#pragma unroll
    for (int u = 0; u < 8; ++u) acc[u] = make_float4(0.f, 0.f, 0.f, 0.f);
    for (int s0 = wid * 16; s0 < SP; s0 += STEP) {
        float4 v4[8];
        float pr[8];
#pragma unroll
        for (int u = 0; u < 8; ++u) {
            const int p = s0 + u * 2 + half;
            const int idx = bt[p >> 4] * PBS + (p & (PBS - 1));
            const float* vp = (idx == slot_b) ? newv
                                              : (v_cache + (size_t)idx * HIDDEN + h * HD);
            v4[u] = *reinterpret_cast<const float4*>(vp + l32 * 4);
            pr[u] = sc[p];
        }
#pragma unroll
        for (int u = 0; u < 8; ++u) {
            acc[u].x += pr[u] * v4[u].x;
            acc[u].y += pr[u] * v4[u].y;
            acc[u].z += pr[u] * v4[u].z;
            acc[u].w += pr[u] * v4[u].w;
        }
    }
    float4 a = acc[0];
#pragma unroll
    for (int u = 1; u < 8; ++u) {
        a.x += acc[u].x; a.y += acc[u].y; a.z += acc[u].z; a.w += acc[u].w;
    }
    a.x += __shfl_xor(a.x, 32, 64);
    a.y += __shfl_xor(a.y, 32, 64);
    a.z += __shfl_xor(a.z, 32, 64);
    a.w += __shfl_xor(a.w, 32, 64);

    if (half == 0)
        *reinterpret_cast<float4*>(&stage[wid * HD + l32 * 4]) = a;
    __syncthreads();
    if (wid == 0) {
        float t0 = 0.f, t1 = 0.f;
        for (int w = 0; w < nw; ++w) {
            t0 += stage[w * HD + lane * 2];
            t1 += stage[w * HD + lane * 2 + 1];
        }
        float* po = part_o + ((size_t)bh * NSPLIT + split) * HD;
        po[lane * 2]     = t0;
        po[lane * 2 + 1] = t1;
        if (lane == 0) {
            part_ml[((size_t)bh * NSPLIT + split) * 2]     = bm;
            part_ml[((size_t)bh * NSPLIT + split) * 2 + 1] = tot;
        }
    }
}

// Combine NSPLIT partials per (b,h). One block per bh, HD threads.
__global__ __launch_bounds__(HD) void attn_reduce(const float* __restrict__ part_o,
                                                  const float* __restrict__ part_ml,
                                                  float* __restrict__ attn_out) {
    const int bh = blockIdx.x;
    const int d  = threadIdx.x;
    float M = -1e30f;
#pragma unroll
    for (int i = 0; i < NSPLIT; ++i)
        M = fmaxf(M, part_ml[((size_t)bh * NSPLIT + i) * 2]);
    float L = 0.f, o = 0.f;
#pragma unroll
    for (int i = 0; i < NSPLIT; ++i) {
        const float mi = part_ml[((size_t)bh * NSPLIT + i) * 2];
        const float li = part_ml[((size_t)bh * NSPLIT + i) * 2 + 1];
        const float w  = __expf(mi - M);
        L += li * w;
        o += part_o[((size_t)bh * NSPLIT + i) * HD + d] * w;
    }
    attn_out[(size_t)bh * HD + d] = o / L;
}

extern "C" void kernel_launch(void* const* d_in, const int* in_sizes, int n_in,
                              void* d_out, int out_size, void* d_ws, size_t ws_size,
                              hipStream_t stream) {
    const float* hidden  = (const float*)d_in[0];
    const float* cosb    = (const float*)d_in[1];
    const float* sinb    = (const float*)d_in[2];
    const float* w_qkv   = (const float*)d_in[3];
    const float* b_qkv   = (const float*)d_in[4];
    const float* w_o     = (const float*)d_in[5];
    const float* k_cache = (const float*)d_in[6];
    const float* v_cache = (const float*)d_in[7];
    const int*   btab    = (const int*)d_in[8];
    const int*   slots   = (const int*)d_in[9];
    const int*   lens    = (const int*)d_in[10];

    const int B = in_sizes[0] / HIDDEN;      // 8
    const int max_blocks = in_sizes[8] / B;  // 128
    const int S = max_blocks * PBS;          // 2048

    float* qkv     = (float*)d_ws;                        // [B][QKVN]
    float* attn    = qkv + (size_t)B * QKVN;              // [B][HIDDEN]
    float* part_o  = attn + (size_t)B * HIDDEN;           // [B*NH*NSPLIT][HD]
    float* part_ml = part_o + (size_t)B * NH * NSPLIT * HD;  // [B*NH*NSPLIT][2]
    float* out     = (float*)d_out;

    // 1) qkv = hidden @ w_qkv^T + b_qkv   (4 rows per wave)
    gemv4r<<<QKVN / 16, 256, 0, stream>>>(hidden, w_qkv, b_qkv, qkv, QKVN, HIDDEN);

    // 2) RoPE on q and k
    {
        const int total = 2 * B * NH * (HD / 2);
        rope_k<<<(total + 255) / 256, 256, 0, stream>>>(qkv, cosb, sinb, B);
    }

    // 3) paged attention partials + reduce
    {
        const int SP = S / NSPLIT;
        const size_t smem = (size_t)(SP + SP / PBS + 16 + 4 * HD) * sizeof(float);
        attn_part<<<B * NH * NSPLIT, 256, smem, stream>>>(qkv, k_cache, v_cache,
                                                          btab, slots, lens,
                                                          part_o, part_ml, S, max_blocks);
        attn_reduce<<<B * NH, HD, 0, stream>>>(part_o, part_ml, attn);
    }

    // 4) out = attn @ w_o^T
    gemv4r<<<HIDDEN / 16, 256, 0, stream>>>(attn, w_o, nullptr, out, HIDDEN, HIDDEN);
}